// Round 7
// baseline (712.752 us; speedup 1.0000x reference)
//
#include <hip/hip_runtime.h>
#include <math.h>

#define B_    16
#define S_    512
#define D_    768
#define L_    5
#define MAXW  5
#define TOPK  8
#define CAND  16
#define NSPAN (S_*MAXW)    // 2560
#define M_    (B_*S_)      // 8192

typedef __attribute__((ext_vector_type(8))) short s16x8;
typedef __attribute__((ext_vector_type(4))) float f32x4;

__device__ __forceinline__ ushort f2bf(float x) {
    union { float f; unsigned u; } c; c.f = x;
    unsigned r = c.u + 0x7fffu + ((c.u >> 16) & 1u);
    return (ushort)(r >> 16);
}
__device__ __forceinline__ float bf2f(ushort h) {
    union { unsigned u; float f; } c; c.u = ((unsigned)h) << 16;
    return c.f;
}

// ---------------------------------------------------------------------------
__global__ void init_k(int* __restrict__ flag, int v) {
    if (threadIdx.x == 0) *flag = v;
}

// ---------------------------------------------------------------------------
// k-map probe: measures the RELATIVE lane->k mapping between the A and B
// operands of mfma_f32_16x16x32_bf16, independent of row/col/CD layouts.
// A[r] = 2^(lg*8+r) for all lanes; B one-hot at slot w (blockIdx.x).
// Every output element = 2^s where s = kappaA^-1(kappaB(w)).
// kmap[w] = s. Anomaly (non-power, reg/lane disagreement) -> flag |= 8.
// ---------------------------------------------------------------------------
__global__ __launch_bounds__(64)
void kprobe_k(int* __restrict__ kmap, int* __restrict__ flag) {
    const int w = blockIdx.x;          // 0..31: target B slot
    const int l = threadIdx.x;
    const int lg = l >> 4;
    s16x8 af, bf;
    #pragma unroll
    for (int r = 0; r < 8; ++r) {
        const int slot = lg * 8 + r;
        union { float f; unsigned u; } pw; pw.u = (unsigned)(127 + slot) << 23;  // 2^slot
        af[r] = (short)f2bf(pw.f);
        bf[r] = (short)f2bf(slot == w ? 1.f : 0.f);
    }
    f32x4 z = {0.f, 0.f, 0.f, 0.f};
    f32x4 d = __builtin_amdgcn_mfma_f32_16x16x32_bf16(af, bf, z, 0, 0, 0);

    const float v0 = d[0];
    const float vx = __shfl(v0, 32);   // cross-lane consistency sample
    if (l == 0) {
        union { float f; unsigned u; } c0; c0.f = v0;
        const int e = (int)((c0.u >> 23) & 0xFF) - 127;
        bool ok = (v0 > 0.f) && ((c0.u & 0x7FFFFFu) == 0) && e >= 0 && e < 32;
        if (d[1] != v0 || d[2] != v0 || d[3] != v0 || vx != v0) ok = false;
        kmap[w] = ok ? e : w;
        if (!ok) atomicOr(flag, 8);
    }
}

// ---------------------------------------------------------------------------
// Composite output-map probe (as R6) with B packed through kmap, so the
// product structure D[m][n]=(m+1)+32(n+1) holds even when kappaA != kappaB.
// Decodes lane/reg -> (row,col); non-bijective/undecodable -> flag |= 4.
// ---------------------------------------------------------------------------
__global__ __launch_bounds__(64)
void probe_k(const int* __restrict__ kmap, int* __restrict__ rowMap,
             int* __restrict__ colMap, int* __restrict__ flag) {
    __shared__ int seen[256];
    const int l = threadIdx.x;
    const int lr = l & 15, lg = l >> 4;
    #pragma unroll
    for (int r = 0; r < 4; ++r) seen[l * 4 + r] = 0;
    __syncthreads();

    s16x8 af, bf;
    #pragma unroll
    for (int r = 0; r < 8; ++r) {
        const int k = lg * 8 + r;
        const int s = kmap[k] & 31;
        const float av = (k == 0) ? (float)(lr + 1) : ((k == 1) ? 1.f : 0.f);
        const float bv = (s == 0) ? 1.f : ((s == 1) ? 32.f * (float)(lr + 1) : 0.f);
        af[r] = (short)f2bf(av);
        bf[r] = (short)f2bf(bv);
    }
    f32x4 z = {0.f, 0.f, 0.f, 0.f};
    f32x4 d = __builtin_amdgcn_mfma_f32_16x16x32_bf16(af, bf, z, 0, 0, 0);

    int mloc[4], nloc[4];
    bool ok = true;
    #pragma unroll
    for (int r = 0; r < 4; ++r) {
        const float dv = d[r];
        int m, n;
        if (dv >= 32.5f && dv <= 528.5f) {
            const int v = (int)(dv + 0.5f);
            m = (v & 31) - 1;
            n = (v >> 5) - 1;
            if (dv != (float)v || m < 0 || m > 15 || n < 0 || n > 15) {
                ok = false; m = lg * 4 + r; n = lr;
            }
        } else {
            ok = false; m = lg * 4 + r; n = lr;
        }
        mloc[r] = m; nloc[r] = n;
        rowMap[l * 4 + r] = m;
        colMap[l * 4 + r] = n;
    }
    if (!ok) atomicOr(flag, 4);
    #pragma unroll
    for (int r = 0; r < 4; ++r) atomicAdd(&seen[mloc[r] * 16 + nloc[r]], 1);
    __syncthreads();
    #pragma unroll
    for (int r = 0; r < 4; ++r)
        if (seen[l * 4 + r] != 1) atomicOr(flag, 4);
}

// ---------------------------------------------------------------------------
__global__ __launch_bounds__(256)
void cvt_T(const float* __restrict__ X, ushort* __restrict__ hi, ushort* __restrict__ lo,
           const int* __restrict__ flag) {
    if (*flag != 0) return;
    const int i = (blockIdx.x * 256 + threadIdx.x) * 4;
    float4 v = *reinterpret_cast<const float4*>(X + i);
    ushort4 h, l;
    h.x = f2bf(v.x); l.x = f2bf(v.x - bf2f(h.x));
    h.y = f2bf(v.y); l.y = f2bf(v.y - bf2f(h.y));
    h.z = f2bf(v.z); l.z = f2bf(v.z - bf2f(h.z));
    h.w = f2bf(v.w); l.w = f2bf(v.w - bf2f(h.w));
    *reinterpret_cast<ushort4*>(hi + i) = h;
    *reinterpret_cast<ushort4*>(lo + i) = l;
}

// ---------------------------------------------------------------------------
__global__ __launch_bounds__(256)
void cvt_W(const float* __restrict__ W1, ushort* __restrict__ Whi, ushort* __restrict__ Wlo,
           const int* __restrict__ flag) {
    if (*flag != 0) return;
    __shared__ float tl[32][33];
    const int k0 = blockIdx.x * 32, n0 = blockIdx.y * 32;
    const int tx = threadIdx.x & 31, ty = threadIdx.x >> 5;
    const int base = (n0 >= 768) ? 768 : 0;
    const int d0 = n0 & 767;
    #pragma unroll
    for (int it = 0; it < 4; ++it) {
        int rr = ty + it * 8;
        tl[rr][tx] = W1[(size_t)(base + k0 + rr) * 768 + d0 + tx];
    }
    __syncthreads();
    #pragma unroll
    for (int it = 0; it < 4; ++it) {
        int rr = ty + it * 8;
        float v = tl[tx][rr];
        ushort h = f2bf(v);
        size_t o = (size_t)(n0 + rr) * 768 + k0 + tx;
        Whi[o] = h;
        Wlo[o] = f2bf(v - bf2f(h));
    }
}

// ---------------------------------------------------------------------------
// MFMA GEMM: A-side b128 reads (A's coords = reference frame); B-side gathered
// through kmap (corrects kappaA != kappaB); C-write via probe row/col maps.
// ---------------------------------------------------------------------------
__global__ __launch_bounds__(256)
void mm_k(const ushort* __restrict__ Thi, const ushort* __restrict__ Tlo,
          const ushort* __restrict__ Whi, const ushort* __restrict__ Wlo,
          const int* __restrict__ kmap, const int* __restrict__ rowMap,
          const int* __restrict__ colMap, const int* __restrict__ flag,
          float* __restrict__ Aout, float* __restrict__ Bout) {
    if (*flag != 0) return;    // probes found anomaly -> repair path handles it
    __shared__ __align__(16) ushort As[128 * 32];
    __shared__ __align__(16) ushort Bs[128 * 32];
    const int tid = threadIdx.x;
    const int bm = blockIdx.x, bn = blockIdx.y;
    const int row0 = bm * 128;
    const int n0g = bn * 128;

    const int srow = tid >> 2;
    const int scol = (tid & 3) * 8;
    const size_t a_g0 = (size_t)(row0 + srow) * 768 + scol;
    const size_t b_g0 = (size_t)(n0g + srow) * 768 + scol;
    const int l_off = srow * 32 + scol;

    const int lane = tid & 63, wv = tid >> 6;
    const int wr = wv >> 1, wc = wv & 1;
    const int lr = lane & 15, lg = lane >> 4;
    const int ko = lg * 8;

    int rm[4], cm[4], kb[8];
    #pragma unroll
    for (int r = 0; r < 4; ++r) {
        rm[r] = rowMap[lane * 4 + r];
        cm[r] = colMap[lane * 4 + r];
    }
    #pragma unroll
    for (int r = 0; r < 8; ++r) kb[r] = kmap[lg * 8 + r] & 31;

    f32x4 acc[4][4];
    #pragma unroll
    for (int i = 0; i < 4; ++i)
        #pragma unroll
        for (int j = 0; j < 4; ++j) acc[i][j] = f32x4{0.f, 0.f, 0.f, 0.f};

    #pragma unroll 1
    for (int ph = 0; ph < 3; ++ph) {
        const ushort* Asrc = (ph == 1) ? Tlo : Thi;
        const ushort* Bsrc = (ph == 2) ? Wlo : Whi;
        #pragma unroll 1
        for (int jj = 0; jj < 24; ++jj) {
            const int col = jj * 32;
            uint4 a0 = *reinterpret_cast<const uint4*>(Asrc + a_g0 + col);
            uint4 a1 = *reinterpret_cast<const uint4*>(Asrc + a_g0 + col + 64 * 768);
            uint4 b0 = *reinterpret_cast<const uint4*>(Bsrc + b_g0 + col);
            uint4 b1 = *reinterpret_cast<const uint4*>(Bsrc + b_g0 + col + 64 * 768);
            __syncthreads();
            *reinterpret_cast<uint4*>(&As[l_off])           = a0;
            *reinterpret_cast<uint4*>(&As[l_off + 64 * 32]) = a1;
            *reinterpret_cast<uint4*>(&Bs[l_off])           = b0;
            *reinterpret_cast<uint4*>(&Bs[l_off + 64 * 32]) = b1;
            __syncthreads();
            s16x8 af[4], bf[4];
            #pragma unroll
            for (int i = 0; i < 4; ++i)
                af[i] = *reinterpret_cast<const s16x8*>(&As[(wr * 64 + i * 16 + lr) * 32 + ko]);
            #pragma unroll
            for (int j = 0; j < 4; ++j) {
                const int bbase = (wc * 64 + j * 16 + lr) * 32;
                s16x8 t;
                #pragma unroll
                for (int r = 0; r < 8; ++r) t[r] = (short)Bs[bbase + kb[r]];
                bf[j] = t;
            }
            #pragma unroll
            for (int i = 0; i < 4; ++i)
                #pragma unroll
                for (int j = 0; j < 4; ++j)
                    acc[i][j] = __builtin_amdgcn_mfma_f32_16x16x32_bf16(af[i], bf[j], acc[i][j], 0, 0, 0);
        }
    }

    float* Om = (bn < 6) ? Aout : Bout;
    const int cbase = ((bn < 6) ? bn : bn - 6) * 128 + wc * 64;
    #pragma unroll
    for (int i = 0; i < 4; ++i)
        #pragma unroll
        for (int j = 0; j < 4; ++j)
            #pragma unroll
            for (int r = 0; r < 4; ++r)
                Om[(size_t)(row0 + wr * 64 + i * 16 + rm[r]) * 768 + cbase + j * 16 + cm[r]]
                    = acc[i][j][r];
}

// ---------------------------------------------------------------------------
// sampled validation of A/Bm vs exact fp32 dots; mismatch -> flag |= 1
// ---------------------------------------------------------------------------
__global__ __launch_bounds__(64)
void valid_k(const float* __restrict__ T, const float* __restrict__ W1,
             const float* __restrict__ A, const float* __restrict__ Bm,
             int* __restrict__ flag) {
    const int blk = blockIdx.x, lane = threadIdx.x;
    #pragma unroll 1
    for (int j = 0; j < 8; ++j) {
        const int id = blk * 8 + j;
        const int m = (id * 509) & 8191;
        const int n = (id * 251) % 1536;
        const float* w = (n < 768) ? (W1 + n) : (W1 + 768 * 768 + (n - 768));
        float p = 0.f;
        for (int k = lane; k < 768; k += 64)
            p = fmaf(T[(size_t)m * 768 + k], w[(size_t)k * 768], p);
        #pragma unroll
        for (int off = 32; off; off >>= 1) p += __shfl_xor(p, off);
        if (lane == 0) {
            const int nl = (n < 768) ? n : n - 768;
            const float* M = (n < 768) ? A : Bm;
            if (fabsf(p - M[(size_t)m * 768 + nl]) > 0.02f) atomicOr(flag, 1);
        }
    }
}

// ---------------------------------------------------------------------------
// full fp32 GEMM repair: runs iff flag != 0
// ---------------------------------------------------------------------------
__global__ __launch_bounds__(256, 3)
void repair_k(const float* __restrict__ Tm, const float* __restrict__ W1,
              float* __restrict__ Aout, float* __restrict__ Bout,
              const int* __restrict__ flag) {
    if (*flag == 0) return;
    constexpr int K = D_, N = D_;
    __shared__ float As[16][128];
    __shared__ float Bs[16][128];
    const int bm  = blockIdx.x;
    const int bn2 = blockIdx.y;
    const float* W = W1 + (bn2 >= 6 ? (size_t)D_ * D_ : 0);
    float* Om      = (bn2 >= 6) ? Bout : Aout;
    const int bn   = (bn2 >= 6) ? bn2 - 6 : bn2;
    const int tid = threadIdx.x;
    const int row0 = bm * 128, col0 = bn * 128;
    const int tx = tid & 15, ty = tid >> 4;
    float acc[8][8];
    #pragma unroll
    for (int i = 0; i < 8; ++i)
        #pragma unroll
        for (int j = 0; j < 8; ++j) acc[i][j] = 0.f;
    const int arow = tid >> 1;
    const int acol = (tid & 1) * 4;
    const int brow = tid >> 5;
    const int bcol = (tid & 31) * 4;
    const float* Aptr = Tm + (size_t)(row0 + arow) * K + acol;
    const float* Bptr = W  + (size_t)brow * N + col0 + bcol;
    for (int k0 = 0; k0 < K; k0 += 16) {
        #pragma unroll
        for (int r = 0; r < 2; ++r) {
            float4 av = *reinterpret_cast<const float4*>(Aptr + k0 + r * 8);
            As[acol + r*8 + 0][arow] = av.x;
            As[acol + r*8 + 1][arow] = av.y;
            As[acol + r*8 + 2][arow] = av.z;
            As[acol + r*8 + 3][arow] = av.w;
        }
        #pragma unroll
        for (int r = 0; r < 2; ++r) {
            float4 bv = *reinterpret_cast<const float4*>(Bptr + (size_t)(k0 + r*8) * N);
            *reinterpret_cast<float4*>(&Bs[brow + r*8][bcol]) = bv;
        }
        __syncthreads();
        #pragma unroll
        for (int k = 0; k < 16; ++k) {
            float a[8], b[8];
            *reinterpret_cast<float4*>(&a[0]) = *reinterpret_cast<const float4*>(&As[k][ty*8]);
            *reinterpret_cast<float4*>(&a[4]) = *reinterpret_cast<const float4*>(&As[k][ty*8+4]);
            *reinterpret_cast<float4*>(&b[0]) = *reinterpret_cast<const float4*>(&Bs[k][tx*4]);
            *reinterpret_cast<float4*>(&b[4]) = *reinterpret_cast<const float4*>(&Bs[k][tx*4+64]);
            #pragma unroll
            for (int i = 0; i < 8; ++i)
                #pragma unroll
                for (int j = 0; j < 8; ++j)
                    acc[i][j] = fmaf(a[i], b[j], acc[i][j]);
        }
        __syncthreads();
    }
    #pragma unroll
    for (int i = 0; i < 8; ++i) {
        size_t ro = (size_t)(row0 + ty*8 + i) * N + col0;
        float4 v0 = make_float4(acc[i][0], acc[i][1], acc[i][2], acc[i][3]);
        float4 v1 = make_float4(acc[i][4], acc[i][5], acc[i][6], acc[i][7]);
        *reinterpret_cast<float4*>(&Om[ro + tx*4])      = v0;
        *reinterpret_cast<float4*>(&Om[ro + tx*4 + 64]) = v1;
    }
}

// ---------------------------------------------------------------------------
__global__ void w2ws_k(const float* __restrict__ W2, const float* __restrict__ Ws,
                       const float* __restrict__ b2, const float* __restrict__ bs,
                       float* __restrict__ w2ws, float* __restrict__ cc) {
    const int d = blockIdx.x;
    const int lane = threadIdx.x;
    float p = 0.f;
    if (d < D_) {
        const float* row = W2 + (size_t)d * D_;
        for (int i = lane; i < D_; i += 64) p += row[i] * Ws[i];
    } else {
        for (int i = lane; i < D_; i += 64) p += b2[i] * Ws[i];
    }
    #pragma unroll
    for (int off = 32; off; off >>= 1) p += __shfl_xor(p, off);
    if (lane == 0) {
        if (d < D_) w2ws[d] = p;
        else        *cc = p + *bs;
    }
}

__global__ void seqlen_k(const int* __restrict__ mask, int* __restrict__ seqlen) {
    const int b = blockIdx.x;
    const int lane = threadIdx.x;
    int p = 0;
    for (int i = lane; i < S_; i += 64) p += mask[b * S_ + i];
    #pragma unroll
    for (int off = 32; off; off >>= 1) p += __shfl_xor(p, off);
    if (lane == 0) seqlen[b] = p;
}

// ---------------------------------------------------------------------------
__global__ __launch_bounds__(64)
void score_k(const float* __restrict__ A, const float* __restrict__ Bm,
             const float* __restrict__ b1, const float* __restrict__ w2ws,
             const float* __restrict__ cc, const int* __restrict__ seqlen,
             float* __restrict__ scores) {
    const int bsid = blockIdx.x;
    const int b = bsid >> 9, s = bsid & 511;
    const int lane = threadIdx.x;
    float a[12], w[12], bb[12];
    const float* Arow = A + (size_t)bsid * D_;
    #pragma unroll
    for (int i = 0; i < 12; ++i) {
        int d = lane + i * 64;
        a[i]  = Arow[d];
        w[i]  = w2ws[d];
        bb[i] = b1[d];
    }
    const int sl = seqlen[b];
    const float c = *cc;
    #pragma unroll
    for (int w_ = 0; w_ < MAXW; ++w_) {
        const int e = min(s + w_, S_ - 1);
        const float* Brow = Bm + ((size_t)(b << 9) + e) * D_;
        float p = 0.f;
        #pragma unroll
        for (int i = 0; i < 12; ++i) {
            float h = a[i] + Brow[lane + i * 64] + bb[i];
            p = fmaf(fmaxf(h, 0.f), w[i], p);
        }
        #pragma unroll
        for (int off = 32; off; off >>= 1) p += __shfl_xor(p, off);
        if (lane == 0)
            scores[b * NSPAN + s * MAXW + w_] = (s + w_ < sl) ? (p + c) : -1e30f;
    }
}

// ---------------------------------------------------------------------------
__global__ __launch_bounds__(256)
void topk_k(const float* __restrict__ scores, int* __restrict__ cand_idx) {
    __shared__ float sv[NSPAN];
    __shared__ float rv[4];
    __shared__ int   ri[4];
    const int b = blockIdx.x, tid = threadIdx.x;
    for (int i = tid; i < NSPAN; i += 256) sv[i] = scores[b * NSPAN + i];
    __syncthreads();
    for (int k = 0; k < CAND; ++k) {
        float best = -INFINITY; int bi = 1 << 30;
        for (int i = tid; i < NSPAN; i += 256) {
            float v = sv[i];
            if (v > best || (v == best && i < bi)) { best = v; bi = i; }
        }
        #pragma unroll
        for (int off = 32; off; off >>= 1) {
            float ov = __shfl_xor(best, off);
            int   oi = __shfl_xor(bi, off);
            if (ov > best || (ov == best && oi < bi)) { best = ov; bi = oi; }
        }
        if ((tid & 63) == 0) { rv[tid >> 6] = best; ri[tid >> 6] = bi; }
        __syncthreads();
        if (tid == 0) {
            #pragma unroll
            for (int wv = 1; wv < 4; ++wv)
                if (rv[wv] > best || (rv[wv] == best && ri[wv] < bi)) { best = rv[wv]; bi = ri[wv]; }
            cand_idx[b * CAND + k] = bi;
            sv[bi] = -INFINITY;
        }
        __syncthreads();
    }
}

// ---------------------------------------------------------------------------
__global__ __launch_bounds__(256)
void rerank_part(const float* __restrict__ T, const float* __restrict__ W1,
                 const int* __restrict__ cand_idx, float* __restrict__ part) {
    __shared__ float tj[4][384];
    const int bx = blockIdx.x, kq = blockIdx.y;
    const int b = bx >> 2, g = bx & 3;
    const int tid = threadIdx.x;
    const int c0 = b * CAND + g * 4;
    const int seg = (kq & 1) * 384;

    #pragma unroll
    for (int j = 0; j < 4; ++j) {
        const int n = cand_idx[c0 + j];
        const int s = n / MAXW, w = n % MAXW;
        const int row = (kq < 2) ? s : min(s + w, S_ - 1);
        const float* src = T + ((size_t)(b * S_ + row)) * D_ + seg;
        for (int idx = tid; idx < 384; idx += 256) tj[j][idx] = src[idx];
    }
    __syncthreads();

    float acc[4][3];
    #pragma unroll
    for (int j = 0; j < 4; ++j)
        #pragma unroll
        for (int q = 0; q < 3; ++q) acc[j][q] = 0.f;

    const int f0 = kq * 384;
    #pragma unroll 2
    for (int ff = 0; ff < 384; ++ff) {
        const float* wr = W1 + (size_t)(f0 + ff) * D_ + tid;
        const float w0 = wr[0];
        const float w1 = wr[256];
        const float w2 = wr[512];
        #pragma unroll
        for (int j = 0; j < 4; ++j) {
            const float tv = tj[j][ff];
            acc[j][0] = fmaf(tv, w0, acc[j][0]);
            acc[j][1] = fmaf(tv, w1, acc[j][1]);
            acc[j][2] = fmaf(tv, w2, acc[j][2]);
        }
    }
    #pragma unroll
    for (int j = 0; j < 4; ++j)
        #pragma unroll
        for (int q = 0; q < 3; ++q)
            part[((size_t)(kq * 256 + c0 + j)) * D_ + tid + q * 256] = acc[j][q];
}

// ---------------------------------------------------------------------------
__global__ __launch_bounds__(256)
void rerank_red(const float* __restrict__ part, const float* __restrict__ b1,
                const float* __restrict__ w2ws, const float* __restrict__ cc,
                float* __restrict__ cand_h, float* __restrict__ cand_score) {
    __shared__ float red[4];
    const int c = blockIdx.x, tid = threadIdx.x;
    float p = 0.f;
    #pragma unroll
    for (int q = 0; q < 3; ++q) {
        const int d = tid + q * 256;
        float h = part[((size_t)(0 * 256 + c)) * D_ + d]
                + part[((size_t)(1 * 256 + c)) * D_ + d]
                + part[((size_t)(2 * 256 + c)) * D_ + d]
                + part[((size_t)(3 * 256 + c)) * D_ + d] + b1[d];
        h = fmaxf(h, 0.f);
        cand_h[(size_t)c * D_ + d] = h;
        p = fmaf(h, w2ws[d], p);
    }
    #pragma unroll
    for (int off = 32; off; off >>= 1) p += __shfl_xor(p, off);
    if ((tid & 63) == 0) red[tid >> 6] = p;
    __syncthreads();
    if (tid == 0) cand_score[c] = red[0] + red[1] + red[2] + red[3] + *cc;
}

// ---------------------------------------------------------------------------
__global__ void sel_k(const float* __restrict__ cand_score, const int* __restrict__ cand_idx,
                      float* __restrict__ top_rel, int* __restrict__ sel_slot) {
    const int b = blockIdx.x;
    if (threadIdx.x != 0) return;
    float sc[CAND]; int nn[CAND]; bool used[CAND];
    #pragma unroll
    for (int c = 0; c < CAND; ++c) {
        sc[c] = cand_score[b * CAND + c];
        nn[c] = cand_idx[b * CAND + c];
        used[c] = false;
    }
    for (int k = 0; k < TOPK; ++k) {
        float best = -INFINITY; int bi = -1, bn = 1 << 30;
        #pragma unroll
        for (int c = 0; c < CAND; ++c) {
            if (!used[c] && (sc[c] > best || (sc[c] == best && nn[c] < bn))) {
                best = sc[c]; bi = c; bn = nn[c];
            }
        }
        used[bi] = true;
        top_rel[b * TOPK + k] = best;
        sel_slot[b * TOPK + k] = bi;
    }
}

// ---------------------------------------------------------------------------
__global__ __launch_bounds__(256)
void repr2_k(const float* __restrict__ cand_h, const int* __restrict__ sel_slot,
             const float* __restrict__ W2, const float* __restrict__ b2,
             const float* __restrict__ labels, float* __restrict__ sim) {
    const int blk = blockIdx.x;
    const int b = blk >> 3, kk = blk & 7;
    const int tid = threadIdx.x;
    __shared__ float h[D_];
    __shared__ float sr[D_];
    __shared__ float red[4];

    const int c = sel_slot[b * TOPK + kk];
    const float* hp = cand_h + ((size_t)(b * CAND + c)) * D_;
    for (int d = tid; d < D_; d += 256) h[d] = hp[d];
    __syncthreads();

    float r0 = b2[tid], r1 = b2[tid + 256], r2 = b2[tid + 512];
    for (int d = 0; d < D_; ++d) {
        const float hv = h[d];
        const float* Wrow = W2 + (size_t)d * D_;
        r0 = fmaf(hv, Wrow[tid],       r0);
        r1 = fmaf(hv, Wrow[tid + 256], r1);
        r2 = fmaf(hv, Wrow[tid + 512], r2);
    }
    sr[tid] = r0; sr[tid + 256] = r1; sr[tid + 512] = r2;
    __syncthreads();

    const float* lab = labels + (size_t)b * L_ * D_;
    for (int l = 0; l < L_; ++l) {
        float p = 0.f;
        for (int d = tid; d < D_; d += 256) p = fmaf(lab[l * D_ + d], sr[d], p);
        #pragma unroll
        for (int off = 32; off; off >>= 1) p += __shfl_xor(p, off);
        if ((tid & 63) == 0) red[tid >> 6] = p;
        __syncthreads();
        if (tid == 0) sim[(b * L_ + l) * TOPK + kk] = red[0] + red[1] + red[2] + red[3];
        __syncthreads();
    }
}

// ---------------------------------------------------------------------------
__global__ void final_k(const float* __restrict__ top_rel, const float* __restrict__ sim,
                        float* __restrict__ out) {
    const int b = blockIdx.x, tid = threadIdx.x;
    float m = -INFINITY;
    #pragma unroll
    for (int k = 0; k < TOPK; ++k) m = fmaxf(m, top_rel[b * TOPK + k]);
    float wgt[TOPK]; float Z = 0.f;
    #pragma unroll
    for (int k = 0; k < TOPK; ++k) { wgt[k] = expf(top_rel[b * TOPK + k] - m); Z += wgt[k]; }
    if (tid < L_) {
        float acc = 0.f;
        #pragma unroll
        for (int k = 0; k < TOPK; ++k) acc += sim[(b * L_ + tid) * TOPK + k] * wgt[k];
        const float sc = acc / Z;
        out[b * L_ + tid]            = 1.f / (1.f + expf(-sc));
        out[B_ * L_ + b * L_ + tid]  = 1.0f;
    }
}

// ---------------------------------------------------------------------------
extern "C" void kernel_launch(void* const* d_in, const int* in_sizes, int n_in,
                              void* d_out, int out_size, void* d_ws, size_t ws_size,
                              hipStream_t stream) {
    (void)in_sizes; (void)n_in; (void)out_size;
    const float* token_embs = (const float*)d_in[0];
    const int*   token_mask = (const int*)  d_in[1];
    const float* label_embs = (const float*)d_in[2];
    const float* W1 = (const float*)d_in[3];
    const float* b1 = (const float*)d_in[4];
    const float* W2 = (const float*)d_in[5];
    const float* b2 = (const float*)d_in[6];
    const float* Ws = (const float*)d_in[7];
    const float* bs = (const float*)d_in[8];
    float* out = (float*)d_out;

    float* A          = (float*)d_ws;                   // 6291456 f32
    float* Bm         = A + (size_t)M_ * D_;            // 6291456 f32
    float* scores     = Bm + (size_t)M_ * D_;           // 40960
    float* w2ws       = scores + B_ * NSPAN;            // 768
    float* cc         = w2ws + D_;                      // 1
    int*   seqlen     = (int*)(cc + 1);                 // 16
    int*   flag       = seqlen + B_;                    // 1
    float* top_rel    = (float*)(flag + 1);             // 128
    int*   sel_slot   = (int*)(top_rel + B_ * TOPK);    // 128
    int*   cand_idx   = sel_slot + B_ * TOPK;           // 256
    float* cand_score = (float*)(cand_idx + B_ * CAND); // 256
    float* sim        = cand_score + B_ * CAND;         // 640
    int*   rowMap     = (int*)(sim + 640);              // 256
    int*   colMap     = rowMap + 256;                   // 256
    int*   kmap       = colMap + 256;                   // 32
    float* part       = A;                              // 786432 f32 (A dead after topk)
    float* cand_h     = A + 786432;                     // 196608 f32

    ushort* Thi  = (ushort*)(A + 12648448);
    ushort* Tlo  = Thi + (size_t)M_ * D_;
    ushort* WhiT = Tlo + (size_t)M_ * D_;
    ushort* WloT = WhiT + (size_t)2 * D_ * D_;
    const size_t need = 12648448ULL * 4 + (2ULL * M_ * D_ + 4ULL * D_ * D_) * 2;
    const bool use_mfma = (ws_size >= need);

    init_k<<<1, 64, 0, stream>>>(flag, use_mfma ? 0 : 3);
    if (use_mfma) {
        kprobe_k<<<32, 64, 0, stream>>>(kmap, flag);
        probe_k<<<1, 64, 0, stream>>>(kmap, rowMap, colMap, flag);
        cvt_T<<<(M_ * D_) / (256 * 4), 256, 0, stream>>>(token_embs, Thi, Tlo, flag);
        cvt_W<<<dim3(24, 48), 256, 0, stream>>>(W1, WhiT, WloT, flag);
        mm_k <<<dim3(64, 12), 256, 0, stream>>>(Thi, Tlo, WhiT, WloT, kmap, rowMap, colMap,
                                                flag, A, Bm);
        valid_k<<<256, 64, 0, stream>>>(token_embs, W1, A, Bm, flag);
    }
    repair_k<<<dim3(64, 12), 256, 0, stream>>>(token_embs, W1, A, Bm, flag);
    w2ws_k  <<<D_ + 1, 64, 0, stream>>>(W2, Ws, b2, bs, w2ws, cc);
    seqlen_k<<<B_, 64, 0, stream>>>(token_mask, seqlen);
    score_k <<<M_, 64, 0, stream>>>(A, Bm, b1, w2ws, cc, seqlen, scores);
    topk_k  <<<B_, 256, 0, stream>>>(scores, cand_idx);
    rerank_part<<<dim3(64, 4), 256, 0, stream>>>(token_embs, W1, cand_idx, part);
    rerank_red <<<256, 256, 0, stream>>>(part, b1, w2ws, cc, cand_h, cand_score);
    sel_k   <<<B_, 64, 0, stream>>>(cand_score, cand_idx, top_rel, sel_slot);
    repr2_k <<<B_ * TOPK, 256, 0, stream>>>(cand_h, sel_slot, W2, b2, label_embs, sim);
    final_k <<<B_, 64, 0, stream>>>(top_rel, sim, out);
}

// Round 8
// 539.654 us; speedup vs baseline: 1.3208x; 1.3208x over previous
//
#include <hip/hip_runtime.h>
#include <math.h>

#define B_    16
#define S_    512
#define D_    768
#define L_    5
#define MAXW  5
#define TOPK  8
#define CAND  16
#define NSPAN (S_*MAXW)    // 2560
#define M_    (B_*S_)      // 8192

typedef __attribute__((ext_vector_type(8))) short s16x8;
typedef __attribute__((ext_vector_type(4))) float f32x4;

__device__ __forceinline__ ushort f2bf(float x) {
    union { float f; unsigned u; } c; c.f = x;
    unsigned r = c.u + 0x7fffu + ((c.u >> 16) & 1u);
    return (ushort)(r >> 16);
}
__device__ __forceinline__ float bf2f(ushort h) {
    union { unsigned u; float f; } c; c.u = ((unsigned)h) << 16;
    return c.f;
}

// ---------------------------------------------------------------------------
__global__ void init_k(int* __restrict__ flag, int v) {
    if (threadIdx.x == 0) *flag = v;
}

// ---------------------------------------------------------------------------
// k-map probe (validated R7: passed bijectivity on hardware).
// kmap[w] = s means B-operand slot w pairs with A-operand slot s.
// ---------------------------------------------------------------------------
__global__ __launch_bounds__(64)
void kprobe_k(int* __restrict__ kmap, int* __restrict__ flag) {
    const int w = blockIdx.x;          // 0..31: target B slot
    const int l = threadIdx.x;
    const int lg = l >> 4;
    s16x8 af, bf;
    #pragma unroll
    for (int r = 0; r < 8; ++r) {
        const int slot = lg * 8 + r;
        union { float f; unsigned u; } pw; pw.u = (unsigned)(127 + slot) << 23;  // 2^slot
        af[r] = (short)f2bf(pw.f);
        bf[r] = (short)f2bf(slot == w ? 1.f : 0.f);
    }
    f32x4 z = {0.f, 0.f, 0.f, 0.f};
    f32x4 d = __builtin_amdgcn_mfma_f32_16x16x32_bf16(af, bf, z, 0, 0, 0);

    const float v0 = d[0];
    const float vx = __shfl(v0, 32);
    if (l == 0) {
        union { float f; unsigned u; } c0; c0.f = v0;
        const int e = (int)((c0.u >> 23) & 0xFF) - 127;
        bool ok = (v0 > 0.f) && ((c0.u & 0x7FFFFFu) == 0) && e >= 0 && e < 32;
        if (d[1] != v0 || d[2] != v0 || d[3] != v0 || vx != v0) ok = false;
        kmap[w] = ok ? e : w;
        if (!ok) atomicOr(flag, 8);
    }
}

// ---------------------------------------------------------------------------
// Composite output-map probe with kmap-corrected B packing (passed on HW, R7).
// ---------------------------------------------------------------------------
__global__ __launch_bounds__(64)
void probe_k(const int* __restrict__ kmap, int* __restrict__ rowMap,
             int* __restrict__ colMap, int* __restrict__ flag) {
    __shared__ int seen[256];
    const int l = threadIdx.x;
    const int lr = l & 15, lg = l >> 4;
    #pragma unroll
    for (int r = 0; r < 4; ++r) seen[l * 4 + r] = 0;
    __syncthreads();

    s16x8 af, bf;
    #pragma unroll
    for (int r = 0; r < 8; ++r) {
        const int k = lg * 8 + r;
        const int s = kmap[k] & 31;
        const float av = (k == 0) ? (float)(lr + 1) : ((k == 1) ? 1.f : 0.f);
        const float bv = (s == 0) ? 1.f : ((s == 1) ? 32.f * (float)(lr + 1) : 0.f);
        af[r] = (short)f2bf(av);
        bf[r] = (short)f2bf(bv);
    }
    f32x4 z = {0.f, 0.f, 0.f, 0.f};
    f32x4 d = __builtin_amdgcn_mfma_f32_16x16x32_bf16(af, bf, z, 0, 0, 0);

    int mloc[4], nloc[4];
    bool ok = true;
    #pragma unroll
    for (int r = 0; r < 4; ++r) {
        const float dv = d[r];
        int m, n;
        if (dv >= 32.5f && dv <= 528.5f) {
            const int v = (int)(dv + 0.5f);
            m = (v & 31) - 1;
            n = (v >> 5) - 1;
            if (dv != (float)v || m < 0 || m > 15 || n < 0 || n > 15) {
                ok = false; m = lg * 4 + r; n = lr;
            }
        } else {
            ok = false; m = lg * 4 + r; n = lr;
        }
        mloc[r] = m; nloc[r] = n;
        rowMap[l * 4 + r] = m;
        colMap[l * 4 + r] = n;
    }
    if (!ok) atomicOr(flag, 4);
    #pragma unroll
    for (int r = 0; r < 4; ++r) atomicAdd(&seen[mloc[r] * 16 + nloc[r]], 1);
    __syncthreads();
    #pragma unroll
    for (int r = 0; r < 4; ++r)
        if (seen[l * 4 + r] != 1) atomicOr(flag, 4);
}

// ---------------------------------------------------------------------------
__global__ __launch_bounds__(256)
void cvt_T(const float* __restrict__ X, ushort* __restrict__ hi, ushort* __restrict__ lo,
           const int* __restrict__ flag) {
    if (*flag != 0) return;
    const int i = (blockIdx.x * 256 + threadIdx.x) * 4;
    float4 v = *reinterpret_cast<const float4*>(X + i);
    ushort4 h, l;
    h.x = f2bf(v.x); l.x = f2bf(v.x - bf2f(h.x));
    h.y = f2bf(v.y); l.y = f2bf(v.y - bf2f(h.y));
    h.z = f2bf(v.z); l.z = f2bf(v.z - bf2f(h.z));
    h.w = f2bf(v.w); l.w = f2bf(v.w - bf2f(h.w));
    *reinterpret_cast<ushort4*>(hi + i) = h;
    *reinterpret_cast<ushort4*>(lo + i) = l;
}

// ---------------------------------------------------------------------------
// W1 -> transposed bf16 hi/lo with the kmap k-permutation FOLDED IN:
// Wt[n][32g + slot] = W1_T[n][32g + kmap[slot]], so mm_k's contiguous
// b128 B-reads deliver exactly what the R7 gather delivered.
// ---------------------------------------------------------------------------
__global__ __launch_bounds__(256)
void cvt_W(const float* __restrict__ W1, ushort* __restrict__ Whi, ushort* __restrict__ Wlo,
           const int* __restrict__ kmap, const int* __restrict__ flag) {
    if (*flag != 0) return;
    __shared__ float tl[32][33];
    const int k0 = blockIdx.x * 32, n0 = blockIdx.y * 32;   // k0 is 32-aligned
    const int tx = threadIdx.x & 31, ty = threadIdx.x >> 5;
    const int base = (n0 >= 768) ? 768 : 0;
    const int d0 = n0 & 767;
    const int ksrc = kmap[tx] & 31;
    #pragma unroll
    for (int it = 0; it < 4; ++it) {
        int rr = ty + it * 8;
        tl[rr][tx] = W1[(size_t)(base + k0 + rr) * 768 + d0 + tx];
    }
    __syncthreads();
    #pragma unroll
    for (int it = 0; it < 4; ++it) {
        int rr = ty + it * 8;
        float v = tl[ksrc][rr];          // k-permuted transpose
        ushort h = f2bf(v);
        size_t o = (size_t)(n0 + rr) * 768 + k0 + tx;
        Whi[o] = h;
        Wlo[o] = f2bf(v - bf2f(h));
    }
}

// ---------------------------------------------------------------------------
// MFMA GEMM, software-pipelined reg staging:
//   prefetch(st+1 global->regs) overlaps frag-reads + 16 MFMAs of st.
// B k-permutation is pre-applied in cvt_W -> contiguous b128 both sides.
// C-write via probe-discovered rowMap/colMap.
// ---------------------------------------------------------------------------
__global__ __launch_bounds__(256)
void mm_k(const ushort* __restrict__ Thi, const ushort* __restrict__ Tlo,
          const ushort* __restrict__ Whi, const ushort* __restrict__ Wlo,
          const int* __restrict__ rowMap, const int* __restrict__ colMap,
          const int* __restrict__ flag,
          float* __restrict__ Aout, float* __restrict__ Bout) {
    if (*flag != 0) return;
    __shared__ __align__(16) ushort As[128 * 32];
    __shared__ __align__(16) ushort Bs[128 * 32];
    const int tid = threadIdx.x;
    const int bm = blockIdx.x, bn = blockIdx.y;
    const int row0 = bm * 128;
    const int n0g = bn * 128;

    const int srow = tid >> 2;
    const int scol = (tid & 3) * 8;
    const size_t a_g0 = (size_t)(row0 + srow) * 768 + scol;
    const size_t b_g0 = (size_t)(n0g + srow) * 768 + scol;
    const int l_off = srow * 32 + scol;

    const int lane = tid & 63, wv = tid >> 6;
    const int wr = wv >> 1, wc = wv & 1;
    const int lr = lane & 15, lg = lane >> 4;
    const int ko = lg * 8;

    int rm[4], cm[4];
    #pragma unroll
    for (int r = 0; r < 4; ++r) {
        rm[r] = rowMap[lane * 4 + r];
        cm[r] = colMap[lane * 4 + r];
    }

    f32x4 acc[4][4];
    #pragma unroll
    for (int i = 0; i < 4; ++i)
        #pragma unroll
        for (int j = 0; j < 4; ++j) acc[i][j] = f32x4{0.f, 0.f, 0.f, 0.f};

    // prefetch step 0
    uint4 ra0 = *reinterpret_cast<const uint4*>(Thi + a_g0);
    uint4 ra1 = *reinterpret_cast<const uint4*>(Thi + a_g0 + 64 * 768);
    uint4 rb0 = *reinterpret_cast<const uint4*>(Whi + b_g0);
    uint4 rb1 = *reinterpret_cast<const uint4*>(Whi + b_g0 + 64 * 768);

    #pragma unroll 1
    for (int st = 0; st < 72; ++st) {
        __syncthreads();   // previous iteration's fragment reads complete
        *reinterpret_cast<uint4*>(&As[l_off])           = ra0;
        *reinterpret_cast<uint4*>(&As[l_off + 64 * 32]) = ra1;
        *reinterpret_cast<uint4*>(&Bs[l_off])           = rb0;
        *reinterpret_cast<uint4*>(&Bs[l_off + 64 * 32]) = rb1;
        __syncthreads();   // tile published

        if (st < 71) {     // prefetch next step; latency hides under MFMAs
            const int nst = st + 1;
            const int c = (nst % 24) * 32;
            const ushort* Ap = (nst < 24) ? Thi : ((nst < 48) ? Tlo : Thi);
            const ushort* Bp = (nst < 48) ? Whi : Wlo;
            ra0 = *reinterpret_cast<const uint4*>(Ap + a_g0 + c);
            ra1 = *reinterpret_cast<const uint4*>(Ap + a_g0 + c + 64 * 768);
            rb0 = *reinterpret_cast<const uint4*>(Bp + b_g0 + c);
            rb1 = *reinterpret_cast<const uint4*>(Bp + b_g0 + c + 64 * 768);
        }

        s16x8 af[4], bf[4];
        #pragma unroll
        for (int i = 0; i < 4; ++i)
            af[i] = *reinterpret_cast<const s16x8*>(&As[(wr * 64 + i * 16 + lr) * 32 + ko]);
        #pragma unroll
        for (int j = 0; j < 4; ++j)
            bf[j] = *reinterpret_cast<const s16x8*>(&Bs[(wc * 64 + j * 16 + lr) * 32 + ko]);
        #pragma unroll
        for (int i = 0; i < 4; ++i)
            #pragma unroll
            for (int j = 0; j < 4; ++j)
                acc[i][j] = __builtin_amdgcn_mfma_f32_16x16x32_bf16(af[i], bf[j], acc[i][j], 0, 0, 0);
    }

    float* Om = (bn < 6) ? Aout : Bout;
    const int cbase = ((bn < 6) ? bn : bn - 6) * 128 + wc * 64;
    #pragma unroll
    for (int i = 0; i < 4; ++i)
        #pragma unroll
        for (int j = 0; j < 4; ++j)
            #pragma unroll
            for (int r = 0; r < 4; ++r)
                Om[(size_t)(row0 + wr * 64 + i * 16 + rm[r]) * 768 + cbase + j * 16 + cm[r]]
                    = acc[i][j][r];
}

// ---------------------------------------------------------------------------
// sampled validation of A/Bm vs exact fp32 dots; mismatch -> flag |= 1
// ---------------------------------------------------------------------------
__global__ __launch_bounds__(64)
void valid_k(const float* __restrict__ T, const float* __restrict__ W1,
             const float* __restrict__ A, const float* __restrict__ Bm,
             int* __restrict__ flag) {
    const int blk = blockIdx.x, lane = threadIdx.x;
    #pragma unroll 1
    for (int j = 0; j < 8; ++j) {
        const int id = blk * 8 + j;
        const int m = (id * 509) & 8191;
        const int n = (id * 251) % 1536;
        const float* w = (n < 768) ? (W1 + n) : (W1 + 768 * 768 + (n - 768));
        float p = 0.f;
        for (int k = lane; k < 768; k += 64)
            p = fmaf(T[(size_t)m * 768 + k], w[(size_t)k * 768], p);
        #pragma unroll
        for (int off = 32; off; off >>= 1) p += __shfl_xor(p, off);
        if (lane == 0) {
            const int nl = (n < 768) ? n : n - 768;
            const float* M = (n < 768) ? A : Bm;
            if (fabsf(p - M[(size_t)m * 768 + nl]) > 0.02f) atomicOr(flag, 1);
        }
    }
}

// ---------------------------------------------------------------------------
// full fp32 GEMM repair: runs iff flag != 0
// ---------------------------------------------------------------------------
__global__ __launch_bounds__(256, 3)
void repair_k(const float* __restrict__ Tm, const float* __restrict__ W1,
              float* __restrict__ Aout, float* __restrict__ Bout,
              const int* __restrict__ flag) {
    if (*flag == 0) return;
    constexpr int K = D_, N = D_;
    __shared__ float As[16][128];
    __shared__ float Bs[16][128];
    const int bm  = blockIdx.x;
    const int bn2 = blockIdx.y;
    const float* W = W1 + (bn2 >= 6 ? (size_t)D_ * D_ : 0);
    float* Om      = (bn2 >= 6) ? Bout : Aout;
    const int bn   = (bn2 >= 6) ? bn2 - 6 : bn2;
    const int tid = threadIdx.x;
    const int row0 = bm * 128, col0 = bn * 128;
    const int tx = tid & 15, ty = tid >> 4;
    float acc[8][8];
    #pragma unroll
    for (int i = 0; i < 8; ++i)
        #pragma unroll
        for (int j = 0; j < 8; ++j) acc[i][j] = 0.f;
    const int arow = tid >> 1;
    const int acol = (tid & 1) * 4;
    const int brow = tid >> 5;
    const int bcol = (tid & 31) * 4;
    const float* Aptr = Tm + (size_t)(row0 + arow) * K + acol;
    const float* Bptr = W  + (size_t)brow * N + col0 + bcol;
    for (int k0 = 0; k0 < K; k0 += 16) {
        #pragma unroll
        for (int r = 0; r < 2; ++r) {
            float4 av = *reinterpret_cast<const float4*>(Aptr + k0 + r * 8);
            As[acol + r*8 + 0][arow] = av.x;
            As[acol + r*8 + 1][arow] = av.y;
            As[acol + r*8 + 2][arow] = av.z;
            As[acol + r*8 + 3][arow] = av.w;
        }
        #pragma unroll
        for (int r = 0; r < 2; ++r) {
            float4 bv = *reinterpret_cast<const float4*>(Bptr + (size_t)(k0 + r*8) * N);
            *reinterpret_cast<float4*>(&Bs[brow + r*8][bcol]) = bv;
        }
        __syncthreads();
        #pragma unroll
        for (int k = 0; k < 16; ++k) {
            float a[8], b[8];
            *reinterpret_cast<float4*>(&a[0]) = *reinterpret_cast<const float4*>(&As[k][ty*8]);
            *reinterpret_cast<float4*>(&a[4]) = *reinterpret_cast<const float4*>(&As[k][ty*8+4]);
            *reinterpret_cast<float4*>(&b[0]) = *reinterpret_cast<const float4*>(&Bs[k][tx*4]);
            *reinterpret_cast<float4*>(&b[4]) = *reinterpret_cast<const float4*>(&Bs[k][tx*4+64]);
            #pragma unroll
            for (int i = 0; i < 8; ++i)
                #pragma unroll
                for (int j = 0; j < 8; ++j)
                    acc[i][j] = fmaf(a[i], b[j], acc[i][j]);
        }
        __syncthreads();
    }
    #pragma unroll
    for (int i = 0; i < 8; ++i) {
        size_t ro = (size_t)(row0 + ty*8 + i) * N + col0;
        float4 v0 = make_float4(acc[i][0], acc[i][1], acc[i][2], acc[i][3]);
        float4 v1 = make_float4(acc[i][4], acc[i][5], acc[i][6], acc[i][7]);
        *reinterpret_cast<float4*>(&Om[ro + tx*4])      = v0;
        *reinterpret_cast<float4*>(&Om[ro + tx*4 + 64]) = v1;
    }
}

// ---------------------------------------------------------------------------
__global__ void w2ws_k(const float* __restrict__ W2, const float* __restrict__ Ws,
                       const float* __restrict__ b2, const float* __restrict__ bs,
                       float* __restrict__ w2ws, float* __restrict__ cc) {
    const int d = blockIdx.x;
    const int lane = threadIdx.x;
    float p = 0.f;
    if (d < D_) {
        const float* row = W2 + (size_t)d * D_;
        for (int i = lane; i < D_; i += 64) p += row[i] * Ws[i];
    } else {
        for (int i = lane; i < D_; i += 64) p += b2[i] * Ws[i];
    }
    #pragma unroll
    for (int off = 32; off; off >>= 1) p += __shfl_xor(p, off);
    if (lane == 0) {
        if (d < D_) w2ws[d] = p;
        else        *cc = p + *bs;
    }
}

__global__ void seqlen_k(const int* __restrict__ mask, int* __restrict__ seqlen) {
    const int b = blockIdx.x;
    const int lane = threadIdx.x;
    int p = 0;
    for (int i = lane; i < S_; i += 64) p += mask[b * S_ + i];
    #pragma unroll
    for (int off = 32; off; off >>= 1) p += __shfl_xor(p, off);
    if (lane == 0) seqlen[b] = p;
}

// ---------------------------------------------------------------------------
__global__ __launch_bounds__(64)
void score_k(const float* __restrict__ A, const float* __restrict__ Bm,
             const float* __restrict__ b1, const float* __restrict__ w2ws,
             const float* __restrict__ cc, const int* __restrict__ seqlen,
             float* __restrict__ scores) {
    const int bsid = blockIdx.x;
    const int b = bsid >> 9, s = bsid & 511;
    const int lane = threadIdx.x;
    float a[12], w[12], bb[12];
    const float* Arow = A + (size_t)bsid * D_;
    #pragma unroll
    for (int i = 0; i < 12; ++i) {
        int d = lane + i * 64;
        a[i]  = Arow[d];
        w[i]  = w2ws[d];
        bb[i] = b1[d];
    }
    const int sl = seqlen[b];
    const float c = *cc;
    #pragma unroll
    for (int w_ = 0; w_ < MAXW; ++w_) {
        const int e = min(s + w_, S_ - 1);
        const float* Brow = Bm + ((size_t)(b << 9) + e) * D_;
        float p = 0.f;
        #pragma unroll
        for (int i = 0; i < 12; ++i) {
            float h = a[i] + Brow[lane + i * 64] + bb[i];
            p = fmaf(fmaxf(h, 0.f), w[i], p);
        }
        #pragma unroll
        for (int off = 32; off; off >>= 1) p += __shfl_xor(p, off);
        if (lane == 0)
            scores[b * NSPAN + s * MAXW + w_] = (s + w_ < sl) ? (p + c) : -1e30f;
    }
}

// ---------------------------------------------------------------------------
__global__ __launch_bounds__(256)
void topk_k(const float* __restrict__ scores, int* __restrict__ cand_idx) {
    __shared__ float sv[NSPAN];
    __shared__ float rv[4];
    __shared__ int   ri[4];
    const int b = blockIdx.x, tid = threadIdx.x;
    for (int i = tid; i < NSPAN; i += 256) sv[i] = scores[b * NSPAN + i];
    __syncthreads();
    for (int k = 0; k < CAND; ++k) {
        float best = -INFINITY; int bi = 1 << 30;
        for (int i = tid; i < NSPAN; i += 256) {
            float v = sv[i];
            if (v > best || (v == best && i < bi)) { best = v; bi = i; }
        }
        #pragma unroll
        for (int off = 32; off; off >>= 1) {
            float ov = __shfl_xor(best, off);
            int   oi = __shfl_xor(bi, off);
            if (ov > best || (ov == best && oi < bi)) { best = ov; bi = oi; }
        }
        if ((tid & 63) == 0) { rv[tid >> 6] = best; ri[tid >> 6] = bi; }
        __syncthreads();
        if (tid == 0) {
            #pragma unroll
            for (int wv = 1; wv < 4; ++wv)
                if (rv[wv] > best || (rv[wv] == best && ri[wv] < bi)) { best = rv[wv]; bi = ri[wv]; }
            cand_idx[b * CAND + k] = bi;
            sv[bi] = -INFINITY;
        }
        __syncthreads();
    }
}

// ---------------------------------------------------------------------------
__global__ __launch_bounds__(256)
void rerank_part(const float* __restrict__ T, const float* __restrict__ W1,
                 const int* __restrict__ cand_idx, float* __restrict__ part) {
    __shared__ float tj[4][384];
    const int bx = blockIdx.x, kq = blockIdx.y;
    const int b = bx >> 2, g = bx & 3;
    const int tid = threadIdx.x;
    const int c0 = b * CAND + g * 4;
    const int seg = (kq & 1) * 384;

    #pragma unroll
    for (int j = 0; j < 4; ++j) {
        const int n = cand_idx[c0 + j];
        const int s = n / MAXW, w = n % MAXW;
        const int row = (kq < 2) ? s : min(s + w, S_ - 1);
        const float* src = T + ((size_t)(b * S_ + row)) * D_ + seg;
        for (int idx = tid; idx < 384; idx += 256) tj[j][idx] = src[idx];
    }
    __syncthreads();

    float acc[4][3];
    #pragma unroll
    for (int j = 0; j < 4; ++j)
        #pragma unroll
        for (int q = 0; q < 3; ++q) acc[j][q] = 0.f;

    const int f0 = kq * 384;
    #pragma unroll 2
    for (int ff = 0; ff < 384; ++ff) {
        const float* wr = W1 + (size_t)(f0 + ff) * D_ + tid;
        const float w0 = wr[0];
        const float w1 = wr[256];
        const float w2 = wr[512];
        #pragma unroll
        for (int j = 0; j < 4; ++j) {
            const float tv = tj[j][ff];
            acc[j][0] = fmaf(tv, w0, acc[j][0]);
            acc[j][1] = fmaf(tv, w1, acc[j][1]);
            acc[j][2] = fmaf(tv, w2, acc[j][2]);
        }
    }
    #pragma unroll
    for (int j = 0; j < 4; ++j)
        #pragma unroll
        for (int q = 0; q < 3; ++q)
            part[((size_t)(kq * 256 + c0 + j)) * D_ + tid + q * 256] = acc[j][q];
}

// ---------------------------------------------------------------------------
__global__ __launch_bounds__(256)
void rerank_red(const float* __restrict__ part, const float* __restrict__ b1,
                const float* __restrict__ w2ws, const float* __restrict__ cc,
                float* __restrict__ cand_h, float* __restrict__ cand_score) {
    __shared__ float red[4];
    const int c = blockIdx.x, tid = threadIdx.x;
    float p = 0.f;
    #pragma unroll
    for (int q = 0; q < 3; ++q) {
        const int d = tid + q * 256;
        float h = part[((size_t)(0 * 256 + c)) * D_ + d]
                + part[((size_t)(1 * 256 + c)) * D_ + d]
                + part[((size_t)(2 * 256 + c)) * D_ + d]
                + part[((size_t)(3 * 256 + c)) * D_ + d] + b1[d];
        h = fmaxf(h, 0.f);
        cand_h[(size_t)c * D_ + d] = h;
        p = fmaf(h, w2ws[d], p);
    }
    #pragma unroll
    for (int off = 32; off; off >>= 1) p += __shfl_xor(p, off);
    if ((tid & 63) == 0) red[tid >> 6] = p;
    __syncthreads();
    if (tid == 0) cand_score[c] = red[0] + red[1] + red[2] + red[3] + *cc;
}

// ---------------------------------------------------------------------------
__global__ void sel_k(const float* __restrict__ cand_score, const int* __restrict__ cand_idx,
                      float* __restrict__ top_rel, int* __restrict__ sel_slot) {
    const int b = blockIdx.x;
    if (threadIdx.x != 0) return;
    float sc[CAND]; int nn[CAND]; bool used[CAND];
    #pragma unroll
    for (int c = 0; c < CAND; ++c) {
        sc[c] = cand_score[b * CAND + c];
        nn[c] = cand_idx[b * CAND + c];
        used[c] = false;
    }
    for (int k = 0; k < TOPK; ++k) {
        float best = -INFINITY; int bi = -1, bn = 1 << 30;
        #pragma unroll
        for (int c = 0; c < CAND; ++c) {
            if (!used[c] && (sc[c] > best || (sc[c] == best && nn[c] < bn))) {
                best = sc[c]; bi = c; bn = nn[c];
            }
        }
        used[bi] = true;
        top_rel[b * TOPK + k] = best;
        sel_slot[b * TOPK + k] = bi;
    }
}

// ---------------------------------------------------------------------------
__global__ __launch_bounds__(256)
void repr2_k(const float* __restrict__ cand_h, const int* __restrict__ sel_slot,
             const float* __restrict__ W2, const float* __restrict__ b2,
             const float* __restrict__ labels, float* __restrict__ sim) {
    const int blk = blockIdx.x;
    const int b = blk >> 3, kk = blk & 7;
    const int tid = threadIdx.x;
    __shared__ float h[D_];
    __shared__ float sr[D_];
    __shared__ float red[4];

    const int c = sel_slot[b * TOPK + kk];
    const float* hp = cand_h + ((size_t)(b * CAND + c)) * D_;
    for (int d = tid; d < D_; d += 256) h[d] = hp[d];
    __syncthreads();

    float r0 = b2[tid], r1 = b2[tid + 256], r2 = b2[tid + 512];
    for (int d = 0; d < D_; ++d) {
        const float hv = h[d];
        const float* Wrow = W2 + (size_t)d * D_;
        r0 = fmaf(hv, Wrow[tid],       r0);
        r1 = fmaf(hv, Wrow[tid + 256], r1);
        r2 = fmaf(hv, Wrow[tid + 512], r2);
    }
    sr[tid] = r0; sr[tid + 256] = r1; sr[tid + 512] = r2;
    __syncthreads();

    const float* lab = labels + (size_t)b * L_ * D_;
    for (int l = 0; l < L_; ++l) {
        float p = 0.f;
        for (int d = tid; d < D_; d += 256) p = fmaf(lab[l * D_ + d], sr[d], p);
        #pragma unroll
        for (int off = 32; off; off >>= 1) p += __shfl_xor(p, off);
        if ((tid & 63) == 0) red[tid >> 6] = p;
        __syncthreads();
        if (tid == 0) sim[(b * L_ + l) * TOPK + kk] = red[0] + red[1] + red[2] + red[3];
        __syncthreads();
    }
}

// ---------------------------------------------------------------------------
__global__ void final_k(const float* __restrict__ top_rel, const float* __restrict__ sim,
                        float* __restrict__ out) {
    const int b = blockIdx.x, tid = threadIdx.x;
    float m = -INFINITY;
    #pragma unroll
    for (int k = 0; k < TOPK; ++k) m = fmaxf(m, top_rel[b * TOPK + k]);
    float wgt[TOPK]; float Z = 0.f;
    #pragma unroll
    for (int k = 0; k < TOPK; ++k) { wgt[k] = expf(top_rel[b * TOPK + k] - m); Z += wgt[k]; }
    if (tid < L_) {
        float acc = 0.f;
        #pragma unroll
        for (int k = 0; k < TOPK; ++k) acc += sim[(b * L_ + tid) * TOPK + k] * wgt[k];
        const float sc = acc / Z;
        out[b * L_ + tid]            = 1.f / (1.f + expf(-sc));
        out[B_ * L_ + b * L_ + tid]  = 1.0f;
    }
}

// ---------------------------------------------------------------------------
extern "C" void kernel_launch(void* const* d_in, const int* in_sizes, int n_in,
                              void* d_out, int out_size, void* d_ws, size_t ws_size,
                              hipStream_t stream) {
    (void)in_sizes; (void)n_in; (void)out_size;
    const float* token_embs = (const float*)d_in[0];
    const int*   token_mask = (const int*)  d_in[1];
    const float* label_embs = (const float*)d_in[2];
    const float* W1 = (const float*)d_in[3];
    const float* b1 = (const float*)d_in[4];
    const float* W2 = (const float*)d_in[5];
    const float* b2 = (const float*)d_in[6];
    const float* Ws = (const float*)d_in[7];
    const float* bs = (const float*)d_in[8];
    float* out = (float*)d_out;

    float* A          = (float*)d_ws;                   // 6291456 f32
    float* Bm         = A + (size_t)M_ * D_;            // 6291456 f32
    float* scores     = Bm + (size_t)M_ * D_;           // 40960
    float* w2ws       = scores + B_ * NSPAN;            // 768
    float* cc         = w2ws + D_;                      // 1
    int*   seqlen     = (int*)(cc + 1);                 // 16
    int*   flag       = seqlen + B_;                    // 1
    float* top_rel    = (float*)(flag + 1);             // 128
    int*   sel_slot   = (int*)(top_rel + B_ * TOPK);    // 128
    int*   cand_idx   = sel_slot + B_ * TOPK;           // 256
    float* cand_score = (float*)(cand_idx + B_ * CAND); // 256
    float* sim        = cand_score + B_ * CAND;         // 640
    int*   rowMap     = (int*)(sim + 640);              // 256
    int*   colMap     = rowMap + 256;                   // 256
    int*   kmap       = colMap + 256;                   // 32
    float* part       = A;                              // 786432 f32 (A dead after topk)
    float* cand_h     = A + 786432;                     // 196608 f32

    ushort* Thi  = (ushort*)(A + 12648448);
    ushort* Tlo  = Thi + (size_t)M_ * D_;
    ushort* WhiT = Tlo + (size_t)M_ * D_;
    ushort* WloT = WhiT + (size_t)2 * D_ * D_;
    const size_t need = 12648448ULL * 4 + (2ULL * M_ * D_ + 4ULL * D_ * D_) * 2;
    const bool use_mfma = (ws_size >= need);

    init_k<<<1, 64, 0, stream>>>(flag, use_mfma ? 0 : 3);
    if (use_mfma) {
        kprobe_k<<<32, 64, 0, stream>>>(kmap, flag);
        probe_k<<<1, 64, 0, stream>>>(kmap, rowMap, colMap, flag);
        cvt_T<<<(M_ * D_) / (256 * 4), 256, 0, stream>>>(token_embs, Thi, Tlo, flag);
        cvt_W<<<dim3(24, 48), 256, 0, stream>>>(W1, WhiT, WloT, kmap, flag);
        mm_k <<<dim3(64, 12), 256, 0, stream>>>(Thi, Tlo, WhiT, WloT, rowMap, colMap,
                                                flag, A, Bm);
        valid_k<<<256, 64, 0, stream>>>(token_embs, W1, A, Bm, flag);
    }
    repair_k<<<dim3(64, 12), 256, 0, stream>>>(token_embs, W1, A, Bm, flag);
    w2ws_k  <<<D_ + 1, 64, 0, stream>>>(W2, Ws, b2, bs, w2ws, cc);
    seqlen_k<<<B_, 64, 0, stream>>>(token_mask, seqlen);
    score_k <<<M_, 64, 0, stream>>>(A, Bm, b1, w2ws, cc, seqlen, scores);
    topk_k  <<<B_, 256, 0, stream>>>(scores, cand_idx);
    rerank_part<<<dim3(64, 4), 256, 0, stream>>>(token_embs, W1, cand_idx, part);
    rerank_red <<<256, 256, 0, stream>>>(part, b1, w2ws, cc, cand_h, cand_score);
    sel_k   <<<B_, 64, 0, stream>>>(cand_score, cand_idx, top_rel, sel_slot);
    repr2_k <<<B_ * TOPK, 256, 0, stream>>>(cand_h, sel_slot, W2, b2, label_embs, sim);
    final_k <<<B_, 64, 0, stream>>>(top_rel, sim, out);
}